// Round 1
// baseline (356.041 us; speedup 1.0000x reference)
//
#include <hip/hip_runtime.h>
#include <hip/hip_fp16.h>
#include <stdint.h>

typedef _Float16 half_t;
typedef half_t half8 __attribute__((ext_vector_type(8)));
typedef float f32x4 __attribute__((ext_vector_type(4)));

#define E4M3_MAX 448.0f

// ---------------------------------------------------------------------------
// Quantization kernel: one 256-thread WG per 128x128 block.
// in: fp32 [R][C] row-major. out: fp16 integer-valued [R][C], scales [R/128][C/128]
// ---------------------------------------------------------------------------
__global__ __launch_bounds__(256) void quant_kernel(const float* __restrict__ in,
                                                    half_t* __restrict__ outq,
                                                    float* __restrict__ scales,
                                                    int C) {
    const int cb = blockIdx.x;   // col block
    const int rb = blockIdx.y;   // row block
    const int tid = threadIdx.x;
    const int col4 = tid & 31;   // float4 index within 128-col row (0..31)
    const int rsub = tid >> 5;   // 0..7 (8 rows per pass, 16 passes)

    const float* base = in + (size_t)(rb * 128 + rsub) * C + cb * 128 + col4 * 4;

    f32x4 v[16];
    float amax = 0.0f;
#pragma unroll
    for (int p = 0; p < 16; ++p) {
        v[p] = *(const f32x4*)(base + (size_t)p * 8 * C);
        amax = fmaxf(amax, fmaxf(fmaxf(fabsf(v[p].x), fabsf(v[p].y)),
                                 fmaxf(fabsf(v[p].z), fabsf(v[p].w))));
    }
    // wave reduce (64 lanes)
#pragma unroll
    for (int off = 32; off > 0; off >>= 1)
        amax = fmaxf(amax, __shfl_xor(amax, off, 64));
    __shared__ float red[4];
    if ((tid & 63) == 0) red[tid >> 6] = amax;
    __syncthreads();
    amax = fmaxf(fmaxf(red[0], red[1]), fmaxf(red[2], red[3]));

    const float scale = fmaxf(amax / E4M3_MAX, 1e-8f);  // exact div, matches ref
    const float rs = 1.0f / scale;                      // RN reciprocal, once

    half_t* obase = outq + (size_t)(rb * 128 + rsub) * C + cb * 128 + col4 * 4;
#pragma unroll
    for (int p = 0; p < 16; ++p) {
        float q0 = fminf(fmaxf(rintf(v[p].x * rs), -E4M3_MAX), E4M3_MAX);
        float q1 = fminf(fmaxf(rintf(v[p].y * rs), -E4M3_MAX), E4M3_MAX);
        float q2 = fminf(fmaxf(rintf(v[p].z * rs), -E4M3_MAX), E4M3_MAX);
        float q3 = fminf(fmaxf(rintf(v[p].w * rs), -E4M3_MAX), E4M3_MAX);
        union { half_t h[4]; uint64_t u; } pk;
        pk.h[0] = (half_t)q0; pk.h[1] = (half_t)q1;
        pk.h[2] = (half_t)q2; pk.h[3] = (half_t)q3;
        *(uint64_t*)(obase + (size_t)p * 8 * C) = pk.u;
    }
    if (tid == 0) scales[(size_t)rb * gridDim.x + cb] = scale;
}

// ---------------------------------------------------------------------------
// NT GEMM: C[M][N] = sum_kb s_x[ib][kb]*s_w[jb][kb] * (Aq[i][:] . Bq[j][:]) + bias[j]
// Aq [M][K] fp16, Bq [N][K] fp16, both row-major (K contiguous).
// 128x128 tile per WG, 4 waves (2x2), BK=64, m97 2-barrier structure,
// global_load_lds width-16 staging, XOR-swizzled LDS (T2, both-sides).
// ---------------------------------------------------------------------------
__device__ __forceinline__ void async_copy16(const void* g, void* l) {
    __builtin_amdgcn_global_load_lds((const __attribute__((address_space(1))) void*)g,
                                     (__attribute__((address_space(3))) void*)l, 16, 0, 0);
}

__global__ __launch_bounds__(256, 2) void gemm_kernel(
    const half_t* __restrict__ A, const half_t* __restrict__ B,
    const float* __restrict__ sA, const float* __restrict__ sB,
    const float* __restrict__ bias, float* __restrict__ C,
    int M, int N, int K) {
    const int NT = N >> 7;   // N tiles
    const int KB = K >> 7;   // K blocks of 128

    // XCD-aware swizzle (grid is divisible by 8 here; guard anyway)
    int bid = blockIdx.x;
    int id = bid;
    if ((gridDim.x & 7) == 0) {
        int cpx = gridDim.x >> 3;
        id = (bid & 7) * cpx + (bid >> 3);
    }
    const int tm = id / NT;
    const int tn = id % NT;

    __shared__ __align__(16) half_t As[128 * 64];
    __shared__ __align__(16) half_t Bs[128 * 64];

    const int tid = threadIdx.x;
    const int lane = tid & 63;
    const int hi = lane >> 4;   // 0..3
    const int lo = lane & 15;   // 0..15
    const int wid = tid >> 6;
    const int wm = wid >> 1;    // 0..1
    const int wn = wid & 1;     // 0..1

    // staging geometry: chunk c covers rows c*32 + tid/8; in-row byte (tid&7)*16
    const int srow = tid >> 3;                       // 0..31
    const int sb = (tid & 7) << 4;                   // in-row byte, 0..112
    const int xoff = (sb ^ ((srow & 7) << 4)) >> 1;  // pre-swizzled src, in elements

    const half_t* Ag0 = A + (size_t)(tm * 128 + srow) * K;
    const half_t* Bg0 = B + (size_t)(tn * 128 + srow) * K;

    f32x4 master[4][4] = {};

    for (int kb = 0; kb < KB; ++kb) {
        f32x4 inner[4][4] = {};
#pragma unroll
        for (int h = 0; h < 2; ++h) {
            const int k0 = (kb << 7) + (h << 6);
            // stage A and B tiles: 4 chunks each, 16B/lane
#pragma unroll
            for (int c = 0; c < 4; ++c)
                async_copy16(Ag0 + (size_t)c * 32 * K + k0 + xoff, As + c * 2048 + tid * 8);
#pragma unroll
            for (int c = 0; c < 4; ++c)
                async_copy16(Bg0 + (size_t)c * 32 * K + k0 + xoff, Bs + c * 2048 + tid * 8);
            __syncthreads();  // compiler drains vmcnt before s_barrier

#pragma unroll
            for (int kk = 0; kk < 2; ++kk) {
                half8 af[4], bf[4];
#pragma unroll
                for (int m = 0; m < 4; ++m) {
                    int row = wm * 64 + m * 16 + lo;
                    int byte = (row << 7) + ((((kk << 6) + (hi << 4))) ^ ((row & 7) << 4));
                    af[m] = *(const half8*)((const char*)As + byte);
                }
#pragma unroll
                for (int n = 0; n < 4; ++n) {
                    int row = wn * 64 + n * 16 + lo;
                    int byte = (row << 7) + ((((kk << 6) + (hi << 4))) ^ ((row & 7) << 4));
                    bf[n] = *(const half8*)((const char*)Bs + byte);
                }
#pragma unroll
                for (int m = 0; m < 4; ++m)
#pragma unroll
                    for (int n = 0; n < 4; ++n)
                        inner[m][n] = __builtin_amdgcn_mfma_f32_16x16x32_f16(
                            af[m], bf[n], inner[m][n], 0, 0, 0);
            }
            __syncthreads();
        }
        const float s = sA[(size_t)tm * KB + kb] * sB[(size_t)tn * KB + kb];
#pragma unroll
        for (int m = 0; m < 4; ++m)
#pragma unroll
            for (int n = 0; n < 4; ++n)
                master[m][n] += s * inner[m][n];
    }

    // epilogue: bias + store fp32
    const int rbase = tm * 128 + wm * 64;
    const int cbase = tn * 128 + wn * 64;
    float bv[4];
#pragma unroll
    for (int n = 0; n < 4; ++n) bv[n] = bias[cbase + n * 16 + lo];
#pragma unroll
    for (int m = 0; m < 4; ++m) {
        const int r0 = rbase + m * 16 + hi * 4;
#pragma unroll
        for (int n = 0; n < 4; ++n) {
            const int cc = cbase + n * 16 + lo;
#pragma unroll
            for (int r = 0; r < 4; ++r)
                C[(size_t)(r0 + r) * N + cc] = master[m][n][r] + bv[n];
        }
    }
}

// ---------------------------------------------------------------------------
extern "C" void kernel_launch(void* const* d_in, const int* in_sizes, int n_in,
                              void* d_out, int out_size, void* d_ws, size_t ws_size,
                              hipStream_t stream) {
    const float* x = (const float*)d_in[0];
    const float* w = (const float*)d_in[1];
    const float* bias = (const float*)d_in[2];
    float* out = (float*)d_out;

    const int N = in_sizes[2];           // 4096 (D_out)
    const int K = in_sizes[1] / N;       // 4096 (D_in)
    const int M = in_sizes[0] / K;       // 8192 (B*S)

    // workspace layout
    const size_t xq_bytes = (size_t)M * K * sizeof(half_t);
    const size_t wq_bytes = (size_t)N * K * sizeof(half_t);
    const size_t sA_bytes = (size_t)(M / 128) * (K / 128) * sizeof(float);
    const size_t sB_bytes = (size_t)(N / 128) * (K / 128) * sizeof(float);
    const size_t needed = xq_bytes + wq_bytes + sA_bytes + sB_bytes;
    if (ws_size < needed) return;  // insufficient scratch — fail loudly (poisoned out)

    half_t* xq = (half_t*)d_ws;
    half_t* wq = (half_t*)((char*)d_ws + xq_bytes);
    float* sxa = (float*)((char*)d_ws + xq_bytes + wq_bytes);
    float* swb = (float*)((char*)d_ws + xq_bytes + wq_bytes + sA_bytes);

    quant_kernel<<<dim3(K / 128, M / 128), 256, 0, stream>>>(x, xq, sxa, K);
    quant_kernel<<<dim3(K / 128, N / 128), 256, 0, stream>>>(w, wq, swb, K);

    const int nwg = (M / 128) * (N / 128);
    gemm_kernel<<<dim3(nwg), 256, 0, stream>>>(xq, wq, sxa, swb, bias, out, M, N, K);
}

// Round 2
// 285.085 us; speedup vs baseline: 1.2489x; 1.2489x over previous
//
#include <hip/hip_runtime.h>
#include <hip/hip_fp16.h>
#include <stdint.h>

typedef _Float16 half_t;
typedef half_t half8 __attribute__((ext_vector_type(8)));
typedef float f32x4 __attribute__((ext_vector_type(4)));

#define E4M3_MAX 448.0f
#define MFMA16 __builtin_amdgcn_mfma_f32_16x16x32_f16

// problem shape (guarded in kernel_launch)
constexpr int Mdim = 8192, Ndim = 4096, Kdim = 4096;
constexpr int NKT = Kdim / 64;     // 64 K-tiles of 64
constexpr int NITER = NKT / 2;     // 32 iterations (2 K-tiles each = one 128 scale block)
constexpr int NKB = Kdim / 128;    // 32 scale blocks
constexpr int NTN = Ndim / 256;    // 16 N-tiles
constexpr int NTM = Mdim / 256;    // 32 M-tiles
// LDS map (bytes): A: b*32768 + h*16384 ; B: 65536 + same ; scales @131072 (8 waves x 32 f32)
constexpr int LDS_BYTES = 131072 + 8 * 32 * 4;

// ---------------------------------------------------------------------------
// Quantization kernel (unchanged from round 1 — passed, memory-bound)
// ---------------------------------------------------------------------------
__global__ __launch_bounds__(256) void quant_kernel(const float* __restrict__ in,
                                                    half_t* __restrict__ outq,
                                                    float* __restrict__ scales,
                                                    int C) {
    const int cb = blockIdx.x, rb = blockIdx.y;
    const int tid = threadIdx.x;
    const int col4 = tid & 31;
    const int rsub = tid >> 5;

    const float* base = in + (size_t)(rb * 128 + rsub) * C + cb * 128 + col4 * 4;

    f32x4 v[16];
    float amax = 0.0f;
#pragma unroll
    for (int p = 0; p < 16; ++p) {
        v[p] = *(const f32x4*)(base + (size_t)p * 8 * C);
        amax = fmaxf(amax, fmaxf(fmaxf(fabsf(v[p].x), fabsf(v[p].y)),
                                 fmaxf(fabsf(v[p].z), fabsf(v[p].w))));
    }
#pragma unroll
    for (int off = 32; off > 0; off >>= 1)
        amax = fmaxf(amax, __shfl_xor(amax, off, 64));
    __shared__ float red[4];
    if ((tid & 63) == 0) red[tid >> 6] = amax;
    __syncthreads();
    amax = fmaxf(fmaxf(red[0], red[1]), fmaxf(red[2], red[3]));

    const float scale = fmaxf(amax / E4M3_MAX, 1e-8f);
    const float rs = 1.0f / scale;

    half_t* obase = outq + (size_t)(rb * 128 + rsub) * C + cb * 128 + col4 * 4;
#pragma unroll
    for (int p = 0; p < 16; ++p) {
        float q0 = fminf(fmaxf(rintf(v[p].x * rs), -E4M3_MAX), E4M3_MAX);
        float q1 = fminf(fmaxf(rintf(v[p].y * rs), -E4M3_MAX), E4M3_MAX);
        float q2 = fminf(fmaxf(rintf(v[p].z * rs), -E4M3_MAX), E4M3_MAX);
        float q3 = fminf(fmaxf(rintf(v[p].w * rs), -E4M3_MAX), E4M3_MAX);
        union { half_t h[4]; uint64_t u; } pk;
        pk.h[0] = (half_t)q0; pk.h[1] = (half_t)q1;
        pk.h[2] = (half_t)q2; pk.h[3] = (half_t)q3;
        *(uint64_t*)(obase + (size_t)p * 8 * C) = pk.u;
    }
    if (tid == 0) scales[(size_t)rb * gridDim.x + cb] = scale;
}

// ---------------------------------------------------------------------------
// 256x256 8-phase counted-vmcnt GEMM (T2 swizzle + T3/T4 pipeline + T5 setprio)
// ---------------------------------------------------------------------------
__device__ __forceinline__ void async16(const half_t* g, char* l) {
    __builtin_amdgcn_global_load_lds((const __attribute__((address_space(1))) void*)g,
                                     (__attribute__((address_space(3))) void*)l, 16, 0, 0);
}

extern __shared__ char smem[];

__global__ __launch_bounds__(512, 2) void gemm_kernel(
    const half_t* __restrict__ A, const half_t* __restrict__ B,
    const float* __restrict__ sA, const float* __restrict__ sB,
    const float* __restrict__ bias, float* __restrict__ C) {

    const int tid = threadIdx.x;
    const int lane = tid & 63;
    const int wid = tid >> 6;          // 0..7
    const int lo = lane & 15, hi = lane >> 4;
    const int wr = wid >> 2;           // 0..1  (M side)
    const int wc = wid & 3;            // 0..3  (N side)

    // XCD-aware swizzle; nwg = 512, divisible by 8
    const int bid = blockIdx.x;
    constexpr int cpx = (NTM * NTN) / 8;
    const int id = (bid & 7) * cpx + (bid >> 3);
    const int tm = id / NTN, tn = id % NTN;

    // ---- per-wave scale products -> LDS (keeps in-loop scale reads off vmcnt) ----
    const int ib = tm * 2 + wr;
    const int jb = tn * 2 + (wc >> 1);
    {
        const int k = lane & 31;   // lanes 32-63 duplicate same value/address: benign
        float s = sA[ib * NKB + k] * sB[jb * NKB + k];
        *(float*)(smem + 131072 + wid * 128 + k * 4) = s;
    }
    __builtin_amdgcn_sched_barrier(0);

    // ---- staging source bases (pre-swizzled global k so LDS dest stays linear) ----
    const int r0 = tid >> 3;                          // 0..63
    const int ks = ((tid & 7) ^ (r0 & 7)) * 8;        // swizzled k-elem offset
    const half_t* Abase = A + (size_t)(tm * 256 + r0) * Kdim + ks;
    const half_t* Bbase = B + (size_t)(tn * 256 + r0) * Kdim + ks;
    char* ldst = smem + tid * 16;

#define STG_A(b, h, kt) do {                                                              \
    async16(Abase + (size_t)((h) * 128) * Kdim + (kt) * 64,                               \
            ldst + (b) * 32768 + (h) * 16384);                                            \
    async16(Abase + (size_t)((h) * 128 + 64) * Kdim + (kt) * 64,                          \
            ldst + (b) * 32768 + (h) * 16384 + 8192); } while (0)
#define STG_B(b, h, kt) do {                                                              \
    async16(Bbase + (size_t)((h) * 128) * Kdim + (kt) * 64,                               \
            ldst + 65536 + (b) * 32768 + (h) * 16384);                                    \
    async16(Bbase + (size_t)((h) * 128 + 64) * Kdim + (kt) * 64,                          \
            ldst + 65536 + (b) * 32768 + (h) * 16384 + 8192); } while (0)

    // ---- prologue: kt0 complete + kt1 B-halves; vmcnt(4) leaves kt1-B in flight ----
    STG_B(0, 0, 0); STG_B(0, 1, 0); STG_A(0, 0, 0); STG_A(0, 1, 0);
    STG_B(1, 0, 1); STG_B(1, 1, 1);
    asm volatile("s_waitcnt vmcnt(4)" ::: "memory");
    __builtin_amdgcn_sched_barrier(0);
    __builtin_amdgcn_s_barrier();
    __builtin_amdgcn_sched_barrier(0);

    // ---- ds_read lane bases (XOR-swizzled; bank-conflict-free, verified r1) ----
    const int aoff0 = lo * 128 + ((hi ^ (lo & 3)) << 4) + (((lo >> 2) & 1) << 6);
    const int aoff1 = aoff0 ^ 64;
    const char* pA0 = smem + wr * 16384 + aoff0;
    const char* pA1 = smem + wr * 16384 + aoff1;
    const char* pB0 = smem + 65536 + (wc >> 1) * 16384 + (wc & 1) * 8192 + aoff0;
    const char* pB1 = smem + 65536 + (wc >> 1) * 16384 + (wc & 1) * 8192 + aoff1;

    f32x4 acc[8][4] = {};
    half8 bfr[4][2];

#define BARSEQ                                                                            \
    __builtin_amdgcn_sched_barrier(0);                                                    \
    __builtin_amdgcn_s_barrier();                                                         \
    __builtin_amdgcn_sched_barrier(0);

#define LDA4(b, q, A00, A01, A10, A11)                                                    \
    half8 A00 = *(const half8*)(pA0 + (b) * 32768 + (2 * (q)) * 2048);                    \
    half8 A01 = *(const half8*)(pA1 + (b) * 32768 + (2 * (q)) * 2048);                    \
    half8 A10 = *(const half8*)(pA0 + (b) * 32768 + (2 * (q) + 1) * 2048);                \
    half8 A11 = *(const half8*)(pA1 + (b) * 32768 + (2 * (q) + 1) * 2048);

#define MFMAQ(q, A00, A01, A10, A11)                                                      \
    __builtin_amdgcn_s_setprio(1);                                                        \
    acc[2*(q)][0]   = MFMA16(A00, bfr[0][0], acc[2*(q)][0],   0, 0, 0);                   \
    acc[2*(q)][1]   = MFMA16(A00, bfr[1][0], acc[2*(q)][1],   0, 0, 0);                   \
    acc[2*(q)][2]   = MFMA16(A00, bfr[2][0], acc[2*(q)][2],   0, 0, 0);                   \
    acc[2*(q)][3]   = MFMA16(A00, bfr[3][0], acc[2*(q)][3],   0, 0, 0);                   \
    acc[2*(q)+1][0] = MFMA16(A10, bfr[0][0], acc[2*(q)+1][0], 0, 0, 0);                   \
    acc[2*(q)+1][1] = MFMA16(A10, bfr[1][0], acc[2*(q)+1][1], 0, 0, 0);                   \
    acc[2*(q)+1][2] = MFMA16(A10, bfr[2][0], acc[2*(q)+1][2], 0, 0, 0);                   \
    acc[2*(q)+1][3] = MFMA16(A10, bfr[3][0], acc[2*(q)+1][3], 0, 0, 0);                   \
    acc[2*(q)][0]   = MFMA16(A01, bfr[0][1], acc[2*(q)][0],   0, 0, 0);                   \
    acc[2*(q)][1]   = MFMA16(A01, bfr[1][1], acc[2*(q)][1],   0, 0, 0);                   \
    acc[2*(q)][2]   = MFMA16(A01, bfr[2][1], acc[2*(q)][2],   0, 0, 0);                   \
    acc[2*(q)][3]   = MFMA16(A01, bfr[3][1], acc[2*(q)][3],   0, 0, 0);                   \
    acc[2*(q)+1][0] = MFMA16(A11, bfr[0][1], acc[2*(q)+1][0], 0, 0, 0);                   \
    acc[2*(q)+1][1] = MFMA16(A11, bfr[1][1], acc[2*(q)+1][1], 0, 0, 0);                   \
    acc[2*(q)+1][2] = MFMA16(A11, bfr[2][1], acc[2*(q)+1][2], 0, 0, 0);                   \
    acc[2*(q)+1][3] = MFMA16(A11, bfr[3][1], acc[2*(q)+1][3], 0, 0, 0);                   \
    __builtin_amdgcn_s_setprio(0);

    for (int i = 0; i < NITER; ++i) {
        const int kta1 = 2 * i + 1;               // A halves of buf1 (this iter's P5-8)
        const int ktb0 = (2 * i + 2) & (NKT - 1); // next buf0 occupant (wraps -> dead)
        const int ktb1 = (2 * i + 3) & (NKT - 1); // next buf1 occupant (wraps -> dead)

        const float s = *(const float*)(smem + 131072 + wid * 128 + i * 4);
        const half_t sh = (half_t)s;
        const half8 s8 = {sh, sh, sh, sh, sh, sh, sh, sh};

        // ---- P1: buf0 q0 (+ B-frag loads) ----
        {
            half8 l00 = *(const half8*)(pB0 + 0 * 2048), l01 = *(const half8*)(pB1 + 0 * 2048);
            half8 l10 = *(const half8*)(pB0 + 1 * 2048), l11 = *(const half8*)(pB1 + 1 * 2048);
            half8 l20 = *(const half8*)(pB0 + 2 * 2048), l21 = *(const half8*)(pB1 + 2 * 2048);
            half8 l30 = *(const half8*)(pB0 + 3 * 2048), l31 = *(const half8*)(pB1 + 3 * 2048);
            LDA4(0, 0, a00, a01, a10, a11)
            BARSEQ
            bfr[0][0] = l00 * s8; bfr[0][1] = l01 * s8;
            bfr[1][0] = l10 * s8; bfr[1][1] = l11 * s8;
            bfr[2][0] = l20 * s8; bfr[2][1] = l21 * s8;
            bfr[3][0] = l30 * s8; bfr[3][1] = l31 * s8;
            MFMAQ(0, a00, a01, a10, a11)
        }
        // ---- P2 ----
        {
            LDA4(0, 1, a00, a01, a10, a11)
            STG_A(1, 0, kta1);
            BARSEQ
            MFMAQ(1, a00, a01, a10, a11)
        }
        // ---- P3 ----
        {
            LDA4(0, 2, a00, a01, a10, a11)
            STG_B(0, 0, ktb0); STG_A(1, 1, kta1);
            BARSEQ
            MFMAQ(2, a00, a01, a10, a11)
        }
        // ---- P4: gate vmcnt(2) ----
        {
            LDA4(0, 3, a00, a01, a10, a11)
            STG_B(0, 1, ktb0);
            asm volatile("s_waitcnt vmcnt(2)" ::: "memory");
            BARSEQ
            MFMAQ(3, a00, a01, a10, a11)
        }
        // ---- P5: buf1 q0 (+ B-frag loads) ----
        {
            half8 l00 = *(const half8*)(pB0 + 32768 + 0 * 2048), l01 = *(const half8*)(pB1 + 32768 + 0 * 2048);
            half8 l10 = *(const half8*)(pB0 + 32768 + 1 * 2048), l11 = *(const half8*)(pB1 + 32768 + 1 * 2048);
            half8 l20 = *(const half8*)(pB0 + 32768 + 2 * 2048), l21 = *(const half8*)(pB1 + 32768 + 2 * 2048);
            half8 l30 = *(const half8*)(pB0 + 32768 + 3 * 2048), l31 = *(const half8*)(pB1 + 32768 + 3 * 2048);
            LDA4(1, 0, a00, a01, a10, a11)
            BARSEQ
            bfr[0][0] = l00 * s8; bfr[0][1] = l01 * s8;
            bfr[1][0] = l10 * s8; bfr[1][1] = l11 * s8;
            bfr[2][0] = l20 * s8; bfr[2][1] = l21 * s8;
            bfr[3][0] = l30 * s8; bfr[3][1] = l31 * s8;
            MFMAQ(0, a00, a01, a10, a11)
        }
        // ---- P6 ----
        {
            LDA4(1, 1, a00, a01, a10, a11)
            STG_A(0, 0, ktb0); STG_A(0, 1, ktb0);
            BARSEQ
            MFMAQ(1, a00, a01, a10, a11)
        }
        // ---- P7 ----
        {
            LDA4(1, 2, a00, a01, a10, a11)
            STG_B(1, 0, ktb1);
            BARSEQ
            MFMAQ(2, a00, a01, a10, a11)
        }
        // ---- P8: gate vmcnt(4) ----
        {
            LDA4(1, 3, a00, a01, a10, a11)
            STG_B(1, 1, ktb1);
            asm volatile("s_waitcnt vmcnt(4)" ::: "memory");
            BARSEQ
            MFMAQ(3, a00, a01, a10, a11)
        }
    }

    // ---- epilogue: bias + fp32 store ----
    const int rbase = tm * 256 + wr * 128;
    const int cbase = tn * 256 + wc * 64;
    float bv0 = bias[cbase + 0 * 16 + lo];
    float bv1 = bias[cbase + 1 * 16 + lo];
    float bv2 = bias[cbase + 2 * 16 + lo];
    float bv3 = bias[cbase + 3 * 16 + lo];
#pragma unroll
    for (int m = 0; m < 8; ++m) {
        const int r0r = rbase + m * 16 + hi * 4;
#pragma unroll
        for (int r = 0; r < 4; ++r) {
            float* crow = C + (size_t)(r0r + r) * Ndim + cbase + lo;
            crow[0]  = acc[m][0][r] + bv0;
            crow[16] = acc[m][1][r] + bv1;
            crow[32] = acc[m][2][r] + bv2;
            crow[48] = acc[m][3][r] + bv3;
        }
    }
}

// ---------------------------------------------------------------------------
extern "C" void kernel_launch(void* const* d_in, const int* in_sizes, int n_in,
                              void* d_out, int out_size, void* d_ws, size_t ws_size,
                              hipStream_t stream) {
    const float* x = (const float*)d_in[0];
    const float* w = (const float*)d_in[1];
    const float* bias = (const float*)d_in[2];
    float* out = (float*)d_out;

    // shape guard: this kernel is specialized to 8192x4096x4096
    if (in_sizes[2] != Ndim || in_sizes[1] != Ndim * Kdim || in_sizes[0] != Mdim * Kdim)
        return;  // leaves d_out poisoned -> fails loudly

    const size_t xq_bytes = (size_t)Mdim * Kdim * sizeof(half_t);
    const size_t wq_bytes = (size_t)Ndim * Kdim * sizeof(half_t);
    const size_t sA_bytes = (size_t)(Mdim / 128) * NKB * sizeof(float);
    const size_t sB_bytes = (size_t)(Ndim / 128) * NKB * sizeof(float);
    if (ws_size < xq_bytes + wq_bytes + sA_bytes + sB_bytes) return;

    half_t* xq = (half_t*)d_ws;
    half_t* wq = (half_t*)((char*)d_ws + xq_bytes);
    float* sxa = (float*)((char*)d_ws + xq_bytes + wq_bytes);
    float* swb = (float*)((char*)d_ws + xq_bytes + wq_bytes + sA_bytes);

    quant_kernel<<<dim3(Kdim / 128, Mdim / 128), 256, 0, stream>>>(x, xq, sxa, Kdim);
    quant_kernel<<<dim3(Kdim / 128, Ndim / 128), 256, 0, stream>>>(w, wq, swb, Kdim);

    // allow >64KB dynamic LDS (idempotent; harmless if already set / unsupported)
    (void)hipFuncSetAttribute((const void*)gemm_kernel,
                              hipFuncAttributeMaxDynamicSharedMemorySize, LDS_BYTES);

    gemm_kernel<<<dim3(NTM * NTN), dim3(512), LDS_BYTES, stream>>>(xq, wq, sxa, swb, bias, out);
}

// Round 4
// 277.983 us; speedup vs baseline: 1.2808x; 1.0255x over previous
//
#include <hip/hip_runtime.h>
#include <hip/hip_fp16.h>
#include <stdint.h>

typedef _Float16 half_t;
typedef half_t half8 __attribute__((ext_vector_type(8)));
typedef float f32x4 __attribute__((ext_vector_type(4)));

#define E4M3_MAX 448.0f
#define MFMA16 __builtin_amdgcn_mfma_f32_16x16x32_f16

// problem shape (guarded in kernel_launch)
constexpr int Mdim = 8192, Ndim = 4096, Kdim = 4096;
constexpr int NKT = Kdim / 64;     // 64 K-tiles of 64
constexpr int NITER = NKT / 2;     // 32 iterations (2 K-tiles = one 128-scale block)
constexpr int NKB = Kdim / 128;    // 32 scale blocks
constexpr int NTN = Ndim / 256;    // 16 N-tiles
constexpr int NTM = Mdim / 256;    // 32 M-tiles
// LDS (bytes): A: b*32768 + slice*8192 ; B: 65536 + b*32768 + (r>>6)*8192 ; scales @131072
constexpr int LDS_BYTES = 131072 + 8 * 32 * 4;   // scales: wid*128 + k*4, max 131072+1020 < this

// ---------------------------------------------------------------------------
// Quantization kernel (unchanged — passed rounds 1-2, memory-bound)
// ---------------------------------------------------------------------------
__global__ __launch_bounds__(256) void quant_kernel(const float* __restrict__ in,
                                                    half_t* __restrict__ outq,
                                                    float* __restrict__ scales,
                                                    int C) {
    const int cb = blockIdx.x, rb = blockIdx.y;
    const int tid = threadIdx.x;
    const int col4 = tid & 31;
    const int rsub = tid >> 5;

    const float* base = in + (size_t)(rb * 128 + rsub) * C + cb * 128 + col4 * 4;

    f32x4 v[16];
    float amax = 0.0f;
#pragma unroll
    for (int p = 0; p < 16; ++p) {
        v[p] = *(const f32x4*)(base + (size_t)p * 8 * C);
        amax = fmaxf(amax, fmaxf(fmaxf(fabsf(v[p].x), fabsf(v[p].y)),
                                 fmaxf(fabsf(v[p].z), fabsf(v[p].w))));
    }
#pragma unroll
    for (int off = 32; off > 0; off >>= 1)
        amax = fmaxf(amax, __shfl_xor(amax, off, 64));
    __shared__ float red[4];
    if ((tid & 63) == 0) red[tid >> 6] = amax;
    __syncthreads();
    amax = fmaxf(fmaxf(red[0], red[1]), fmaxf(red[2], red[3]));

    const float scale = fmaxf(amax / E4M3_MAX, 1e-8f);
    const float rs = 1.0f / scale;

    half_t* obase = outq + (size_t)(rb * 128 + rsub) * C + cb * 128 + col4 * 4;
#pragma unroll
    for (int p = 0; p < 16; ++p) {
        float q0 = fminf(fmaxf(rintf(v[p].x * rs), -E4M3_MAX), E4M3_MAX);
        float q1 = fminf(fmaxf(rintf(v[p].y * rs), -E4M3_MAX), E4M3_MAX);
        float q2 = fminf(fmaxf(rintf(v[p].z * rs), -E4M3_MAX), E4M3_MAX);
        float q3 = fminf(fmaxf(rintf(v[p].w * rs), -E4M3_MAX), E4M3_MAX);
        union { half_t h[4]; uint64_t u; } pk;
        pk.h[0] = (half_t)q0; pk.h[1] = (half_t)q1;
        pk.h[2] = (half_t)q2; pk.h[3] = (half_t)q3;
        *(uint64_t*)(obase + (size_t)p * 8 * C) = pk.u;
    }
    if (tid == 0) scales[(size_t)rb * gridDim.x + cb] = scale;
}

// ---------------------------------------------------------------------------
// 256x256 8-phase GEMM. Wave rows stay in ONE 128-row scale block (single fold,
// no refold -> no same-phase B re-read race). A staged in 64-row slices with a
// 2-phase read window each; uniform 2 loads/phase; gates vmcnt(4)@P4 and @P8,
// every stage >=2 barriers after its region's last read-issue (FIFO-verified).
// ---------------------------------------------------------------------------
__device__ __forceinline__ void async16(const half_t* g, char* l) {
    __builtin_amdgcn_global_load_lds((const __attribute__((address_space(1))) void*)g,
                                     (__attribute__((address_space(3))) void*)l, 16, 0, 0);
}

extern __shared__ char smem[];

__global__ __launch_bounds__(512, 2) void gemm_kernel(
    const half_t* __restrict__ A, const half_t* __restrict__ B,
    const float* __restrict__ sA, const float* __restrict__ sB,
    const float* __restrict__ bias, float* __restrict__ C) {

    const int tid = threadIdx.x;
    const int lane = tid & 63;
    const int wid = tid >> 6;          // 0..7
    const int lo = lane & 15, hi = lane >> 4;
    const int wr = wid >> 2;           // 0..1  (M side)
    const int wc = wid & 3;            // 0..3  (N side)

    // XCD-aware swizzle; nwg = 512, divisible by 8
    const int bid = blockIdx.x;
    constexpr int cpx = (NTM * NTN) / 8;
    const int id = (bid & 7) * cpx + (bid >> 3);
    const int tm = id / NTN, tn = id % NTN;

    // ---- per-wave scale products -> LDS (wave rows all in block ib) ----
    const int ib = tm * 2 + wr;
    const int jb = tn * 2 + (wc >> 1);
    {
        const int k = lane & 31;   // lanes 32-63 duplicate: benign
        float s = sA[ib * NKB + k] * sB[jb * NKB + k];
        *(float*)(smem + 131072 + wid * 128 + k * 4) = s;
    }
    __builtin_amdgcn_sched_barrier(0);

    // ---- staging source bases (pre-swizzled global k; LDS dest linear) ----
    const int r0 = tid >> 3;                          // 0..63
    const int ks = ((tid & 7) ^ (r0 & 7)) * 8;        // swizzled k-elem offset
    const half_t* Abase = A + (size_t)(tm * 256 + r0) * Kdim + ks;
    const half_t* Bbase = B + (size_t)(tn * 256 + r0) * Kdim + ks;
    char* ldstA = smem + tid * 16;
    char* ldstB = smem + 65536 + tid * 16;

    // A slice s (64 global rows, rows s*64 + r0) of K-tile kt -> buf b: ONE async16
#define STG_AS(b, s, kt)                                                                  \
    async16(Abase + (size_t)((s) * 64) * Kdim + (kt) * 64,                                \
            ldstA + (b) * 32768 + (s) * 8192)
    // B half h (128 rows) of K-tile kt -> buf b: TWO async16
#define STG_B(b, h, kt) do {                                                              \
    async16(Bbase + (size_t)((h) * 128) * Kdim + (kt) * 64,                               \
            ldstB + (b) * 32768 + (h) * 16384);                                           \
    async16(Bbase + (size_t)((h) * 128 + 64) * Kdim + (kt) * 64,                          \
            ldstB + (b) * 32768 + (h) * 16384 + 8192); } while (0)

    // ---- prologue: buf0 full (kt0), then B-buf1 (kt1); A-buf1 staged in-loop P1/P2 ----
    STG_B(0, 0, 0); STG_B(0, 1, 0);
    STG_AS(0, 0, 0); STG_AS(0, 1, 0); STG_AS(0, 2, 0); STG_AS(0, 3, 0);
    STG_B(1, 0, 1); STG_B(1, 1, 1);
    asm volatile("s_waitcnt vmcnt(4)" ::: "memory");   // buf0 landed; B-buf1 in flight
    __builtin_amdgcn_sched_barrier(0);
    __builtin_amdgcn_s_barrier();
    __builtin_amdgcn_sched_barrier(0);

    // ---- ds_read lane bases (XOR-swizzled; bank-conflict-free, verified r1/r2) ----
    // A: wave wr, phase q reads slice 2wr+(q>>1), row-in-slice 32(q&1)+lo (+16):
    //    byte = wr*16384 + q*4096 + lo*128 + koff (+2048 for +16 rows)
    const int koff0 = ((hi ^ (lo & 3)) << 4) + (((lo >> 2) & 1) << 6);
    const char* pA0 = smem + wr * 16384 + lo * 128 + koff0;
    const char* pA1 = smem + wr * 16384 + lo * 128 + (koff0 ^ 64);
    const char* pB0 = smem + 65536 + wc * 8192 + lo * 128 + koff0;
    const char* pB1 = smem + 65536 + wc * 8192 + lo * 128 + (koff0 ^ 64);

    f32x4 acc[8][4] = {};
    half8 bfr[4][2];

#define BARSEQ                                                                            \
    __builtin_amdgcn_sched_barrier(0);                                                    \
    __builtin_amdgcn_s_barrier();                                                         \
    __builtin_amdgcn_sched_barrier(0);

#define LDA4(b, q, A00, A01, A10, A11)                                                    \
    half8 A00 = *(const half8*)(pA0 + (b) * 32768 + (q) * 4096);                          \
    half8 A01 = *(const half8*)(pA1 + (b) * 32768 + (q) * 4096);                          \
    half8 A10 = *(const half8*)(pA0 + (b) * 32768 + (q) * 4096 + 2048);                   \
    half8 A11 = *(const half8*)(pA1 + (b) * 32768 + (q) * 4096 + 2048);

#define MFMAQ(q, A00, A01, A10, A11)                                                      \
    __builtin_amdgcn_s_setprio(1);                                                        \
    acc[2*(q)][0]   = MFMA16(A00, bfr[0][0], acc[2*(q)][0],   0, 0, 0);                   \
    acc[2*(q)][1]   = MFMA16(A00, bfr[1][0], acc[2*(q)][1],   0, 0, 0);                   \
    acc[2*(q)][2]   = MFMA16(A00, bfr[2][0], acc[2*(q)][2],   0, 0, 0);                   \
    acc[2*(q)][3]   = MFMA16(A00, bfr[3][0], acc[2*(q)][3],   0, 0, 0);                   \
    acc[2*(q)+1][0] = MFMA16(A10, bfr[0][0], acc[2*(q)+1][0], 0, 0, 0);                   \
    acc[2*(q)+1][1] = MFMA16(A10, bfr[1][0], acc[2*(q)+1][1], 0, 0, 0);                   \
    acc[2*(q)+1][2] = MFMA16(A10, bfr[2][0], acc[2*(q)+1][2], 0, 0, 0);                   \
    acc[2*(q)+1][3] = MFMA16(A10, bfr[3][0], acc[2*(q)+1][3], 0, 0, 0);                   \
    acc[2*(q)][0]   = MFMA16(A01, bfr[0][1], acc[2*(q)][0],   0, 0, 0);                   \
    acc[2*(q)][1]   = MFMA16(A01, bfr[1][1], acc[2*(q)][1],   0, 0, 0);                   \
    acc[2*(q)][2]   = MFMA16(A01, bfr[2][1], acc[2*(q)][2],   0, 0, 0);                   \
    acc[2*(q)][3]   = MFMA16(A01, bfr[3][1], acc[2*(q)][3],   0, 0, 0);                   \
    acc[2*(q)+1][0] = MFMA16(A11, bfr[0][1], acc[2*(q)+1][0], 0, 0, 0);                   \
    acc[2*(q)+1][1] = MFMA16(A11, bfr[1][1], acc[2*(q)+1][1], 0, 0, 0);                   \
    acc[2*(q)+1][2] = MFMA16(A11, bfr[2][1], acc[2*(q)+1][2], 0, 0, 0);                   \
    acc[2*(q)+1][3] = MFMA16(A11, bfr[3][1], acc[2*(q)+1][3], 0, 0, 0);                   \
    __builtin_amdgcn_s_setprio(0);

#define LDB8(b)                                                                           \
    half8 bl00 = *(const half8*)(pB0 + (b) * 32768 + 0 * 2048);                           \
    half8 bl01 = *(const half8*)(pB1 + (b) * 32768 + 0 * 2048);                           \
    half8 bl10 = *(const half8*)(pB0 + (b) * 32768 + 1 * 2048);                           \
    half8 bl11 = *(const half8*)(pB1 + (b) * 32768 + 1 * 2048);                           \
    half8 bl20 = *(const half8*)(pB0 + (b) * 32768 + 2 * 2048);                           \
    half8 bl21 = *(const half8*)(pB1 + (b) * 32768 + 2 * 2048);                           \
    half8 bl30 = *(const half8*)(pB0 + (b) * 32768 + 3 * 2048);                           \
    half8 bl31 = *(const half8*)(pB1 + (b) * 32768 + 3 * 2048);

#define BFOLD                                                                             \
    {                                                                                     \
        const float s_ = *(const float*)(smem + 131072 + wid * 128 + i * 4);              \
        const half_t sh_ = (half_t)s_;                                                    \
        const half8 s8_ = {sh_, sh_, sh_, sh_, sh_, sh_, sh_, sh_};                       \
        bfr[0][0] = bl00 * s8_; bfr[0][1] = bl01 * s8_;                                   \
        bfr[1][0] = bl10 * s8_; bfr[1][1] = bl11 * s8_;                                   \
        bfr[2][0] = bl20 * s8_; bfr[2][1] = bl21 * s8_;                                   \
        bfr[3][0] = bl30 * s8_; bfr[3][1] = bl31 * s8_;                                   \
    }

    for (int i = 0; i < NITER; ++i) {
        const int kA1  = 2 * i + 1;                // A-buf1 content (read P5-P8 this iter)
        const int ktn0 = (2 * i + 2) & (NKT - 1);  // next buf0 (last iter: wraps -> dead)
        const int ktn1 = (2 * i + 3) & (NKT - 1);  // next buf1-B (wraps -> dead)

        // ---- P1: B(buf0) + A(buf0,q0); stage A1 slices 0,2 (free: last read P6 prev) ----
        {
            LDB8(0)
            LDA4(0, 0, a00, a01, a10, a11)
            STG_AS(1, 0, kA1); STG_AS(1, 2, kA1);
            BARSEQ
            BFOLD
            MFMAQ(0, a00, a01, a10, a11)
        }
        // ---- P2: A(buf0,q1); stage A1 slices 1,3 (free: last read P8 prev +2) ----
        {
            LDA4(0, 1, a00, a01, a10, a11)
            STG_AS(1, 1, kA1); STG_AS(1, 3, kA1);
            BARSEQ
            MFMAQ(1, a00, a01, a10, a11)
        }
        // ---- P3: A(buf0,q2); stage B0h0' (B-buf0 read-issue was P1, +2) ----
        {
            LDA4(0, 2, a00, a01, a10, a11)
            STG_B(0, 0, ktn0);
            BARSEQ
            MFMAQ(2, a00, a01, a10, a11)
        }
        // ---- P4: A(buf0,q3); stage B0h1'; GATE vmcnt(4) -> buf1 fully landed ----
        {
            LDA4(0, 3, a00, a01, a10, a11)
            STG_B(0, 1, ktn0);
            asm volatile("s_waitcnt vmcnt(4)" ::: "memory");
            BARSEQ
            MFMAQ(3, a00, a01, a10, a11)
        }
        // ---- P5: B(buf1) + A(buf1,q0); stage A0 slices 0,2' (read-issue P2, +3) ----
        {
            LDB8(1)
            LDA4(1, 0, a00, a01, a10, a11)
            STG_AS(0, 0, ktn0); STG_AS(0, 2, ktn0);
            BARSEQ
            BFOLD
            MFMAQ(0, a00, a01, a10, a11)
        }
        // ---- P6: A(buf1,q1); stage A0 slices 1,3' (read-issue P4, +2) ----
        {
            LDA4(1, 1, a00, a01, a10, a11)
            STG_AS(0, 1, ktn0); STG_AS(0, 3, ktn0);
            BARSEQ
            MFMAQ(1, a00, a01, a10, a11)
        }
        // ---- P7: A(buf1,q2); stage B1h0' (B-buf1 read-issue P5, +2) ----
        {
            LDA4(1, 2, a00, a01, a10, a11)
            STG_B(1, 0, ktn1);
            BARSEQ
            MFMAQ(2, a00, a01, a10, a11)
        }
        // ---- P8: A(buf1,q3); stage B1h1'; GATE vmcnt(4) -> buf0' fully landed ----
        {
            LDA4(1, 3, a00, a01, a10, a11)
            STG_B(1, 1, ktn1);
            asm volatile("s_waitcnt vmcnt(4)" ::: "memory");
            BARSEQ
            MFMAQ(3, a00, a01, a10, a11)
        }
    }

    // drain in-flight dead stages before workgroup teardown
    asm volatile("s_waitcnt vmcnt(0)" ::: "memory");

    // ---- epilogue: bias + fp32 store (acc[m] row = 128wr + 16m + 4hi + r) ----
    const int rbase = tm * 256 + wr * 128;
    const int cbase = tn * 256 + wc * 64;
    float bv0 = bias[cbase + 0 * 16 + lo];
    float bv1 = bias[cbase + 1 * 16 + lo];
    float bv2 = bias[cbase + 2 * 16 + lo];
    float bv3 = bias[cbase + 3 * 16 + lo];
#pragma unroll
    for (int m = 0; m < 8; ++m) {
        const int r0r = rbase + m * 16 + hi * 4;
#pragma unroll
        for (int r = 0; r < 4; ++r) {
            float* crow = C + (size_t)(r0r + r) * Ndim + cbase + lo;
            crow[0]  = acc[m][0][r] + bv0;
            crow[16] = acc[m][1][r] + bv1;
            crow[32] = acc[m][2][r] + bv2;
            crow[48] = acc[m][3][r] + bv3;
        }
    }
}

// ---------------------------------------------------------------------------
extern "C" void kernel_launch(void* const* d_in, const int* in_sizes, int n_in,
                              void* d_out, int out_size, void* d_ws, size_t ws_size,
                              hipStream_t stream) {
    const float* x = (const float*)d_in[0];
    const float* w = (const float*)d_in[1];
    const float* bias = (const float*)d_in[2];
    float* out = (float*)d_out;

    if (in_sizes[2] != Ndim || in_sizes[1] != Ndim * Kdim || in_sizes[0] != Mdim * Kdim)
        return;  // shape-specialized; fail loudly

    const size_t xq_bytes = (size_t)Mdim * Kdim * sizeof(half_t);
    const size_t wq_bytes = (size_t)Ndim * Kdim * sizeof(half_t);
    const size_t sA_bytes = (size_t)(Mdim / 128) * NKB * sizeof(float);
    const size_t sB_bytes = (size_t)(Ndim / 128) * NKB * sizeof(float);
    if (ws_size < xq_bytes + wq_bytes + sA_bytes + sB_bytes) return;

    half_t* xq = (half_t*)d_ws;
    half_t* wq = (half_t*)((char*)d_ws + xq_bytes);
    float* sxa = (float*)((char*)d_ws + xq_bytes + wq_bytes);
    float* swb = (float*)((char*)d_ws + xq_bytes + wq_bytes + sA_bytes);

    quant_kernel<<<dim3(Kdim / 128, Mdim / 128), 256, 0, stream>>>(x, xq, sxa, Kdim);
    quant_kernel<<<dim3(Kdim / 128, Ndim / 128), 256, 0, stream>>>(w, wq, swb, Kdim);

    (void)hipFuncSetAttribute((const void*)gemm_kernel,
                              hipFuncAttributeMaxDynamicSharedMemorySize, LDS_BYTES);

    gemm_kernel<<<dim3(NTM * NTN), dim3(512), LDS_BYTES, stream>>>(xq, wq, sxa, swb, bias, out);
}

// Round 5
// 275.718 us; speedup vs baseline: 1.2913x; 1.0082x over previous
//
#include <hip/hip_runtime.h>
#include <hip/hip_fp16.h>
#include <stdint.h>

typedef _Float16 half_t;
typedef half_t half8 __attribute__((ext_vector_type(8)));
typedef float f32x4 __attribute__((ext_vector_type(4)));

#define E4M3_MAX 448.0f
#define MFMA16 __builtin_amdgcn_mfma_f32_16x16x32_f16

// problem shape (guarded in kernel_launch)
constexpr int Mdim = 8192, Ndim = 4096, Kdim = 4096;
constexpr int NKT = Kdim / 64;     // 64 K-tiles of 64
constexpr int NITER = NKT / 2;     // 32 iterations (2 K-tiles each)
constexpr int NTN = Ndim / 256;    // 16 N-tiles
constexpr int NTM = Mdim / 256;    // 32 M-tiles
// LDS (bytes): A: b*32768 + slice*8192 ; B: 65536 + b*32768 + region*8192
constexpr int LDS_BYTES = 131072;

// ---------------------------------------------------------------------------
// Quantization kernel: one WG per 128x128 block; writes DEQUANTIZED fp16
// dq = fp16(clip(round(x/s)) * s).  |dq| <= amax (~N(0,1) scale), fp16-safe.
// ---------------------------------------------------------------------------
__global__ __launch_bounds__(256) void quant_kernel(const float* __restrict__ in,
                                                    half_t* __restrict__ outq,
                                                    int C) {
    const int cb = blockIdx.x, rb = blockIdx.y;
    const int tid = threadIdx.x;
    const int col4 = tid & 31;
    const int rsub = tid >> 5;

    const float* base = in + (size_t)(rb * 128 + rsub) * C + cb * 128 + col4 * 4;

    f32x4 v[16];
    float amax = 0.0f;
#pragma unroll
    for (int p = 0; p < 16; ++p) {
        v[p] = *(const f32x4*)(base + (size_t)p * 8 * C);
        amax = fmaxf(amax, fmaxf(fmaxf(fabsf(v[p].x), fabsf(v[p].y)),
                                 fmaxf(fabsf(v[p].z), fabsf(v[p].w))));
    }
#pragma unroll
    for (int off = 32; off > 0; off >>= 1)
        amax = fmaxf(amax, __shfl_xor(amax, off, 64));
    __shared__ float red[4];
    if ((tid & 63) == 0) red[tid >> 6] = amax;
    __syncthreads();
    amax = fmaxf(fmaxf(red[0], red[1]), fmaxf(red[2], red[3]));

    const float scale = fmaxf(amax / E4M3_MAX, 1e-8f);
    const float rs = 1.0f / scale;

    half_t* obase = outq + (size_t)(rb * 128 + rsub) * C + cb * 128 + col4 * 4;
#pragma unroll
    for (int p = 0; p < 16; ++p) {
        float q0 = fminf(fmaxf(rintf(v[p].x * rs), -E4M3_MAX), E4M3_MAX) * scale;
        float q1 = fminf(fmaxf(rintf(v[p].y * rs), -E4M3_MAX), E4M3_MAX) * scale;
        float q2 = fminf(fmaxf(rintf(v[p].z * rs), -E4M3_MAX), E4M3_MAX) * scale;
        float q3 = fminf(fmaxf(rintf(v[p].w * rs), -E4M3_MAX), E4M3_MAX) * scale;
        union { half_t h[4]; uint64_t u; } pk;
        pk.h[0] = (half_t)q0; pk.h[1] = (half_t)q1;
        pk.h[2] = (half_t)q2; pk.h[3] = (half_t)q3;
        *(uint64_t*)(obase + (size_t)p * 8 * C) = pk.u;
    }
}

// ---------------------------------------------------------------------------
// Pure fp16 256x256 8-phase GEMM (m201 template). A staged in 64-row slices
// (2-phase read window each); uniform 2 loads/phase; gates vmcnt(4)@P4/@P8;
// every stage >=2 barriers after its region's last read-issue (round-4 verified).
// ---------------------------------------------------------------------------
__device__ __forceinline__ void async16(const half_t* g, char* l) {
    __builtin_amdgcn_global_load_lds((const __attribute__((address_space(1))) void*)g,
                                     (__attribute__((address_space(3))) void*)l, 16, 0, 0);
}

extern __shared__ char smem[];

__global__ __launch_bounds__(512, 2) void gemm_kernel(
    const half_t* __restrict__ A, const half_t* __restrict__ B,
    const float* __restrict__ bias, float* __restrict__ C) {

    const int tid = threadIdx.x;
    const int lane = tid & 63;
    const int wid = tid >> 6;          // 0..7
    const int lo = lane & 15, hi = lane >> 4;
    const int wr = wid >> 2;           // 0..1  (M side)
    const int wc = wid & 3;            // 0..3  (N side)

    // XCD-aware swizzle; nwg = 512, divisible by 8
    const int bid = blockIdx.x;
    constexpr int cpx = (NTM * NTN) / 8;
    const int id = (bid & 7) * cpx + (bid >> 3);
    const int tm = id / NTN, tn = id % NTN;

    // ---- staging source bases (pre-swizzled global k; LDS dest linear) ----
    const int r0 = tid >> 3;                          // 0..63
    const int ks = ((tid & 7) ^ (r0 & 7)) * 8;        // swizzled k-elem offset
    const half_t* Abase = A + (size_t)(tm * 256 + r0) * Kdim + ks;
    const half_t* Bbase = B + (size_t)(tn * 256 + r0) * Kdim + ks;
    char* ldstA = smem + tid * 16;
    char* ldstB = smem + 65536 + tid * 16;

    // A slice s (64 global rows) of K-tile kt -> buf b: ONE async16
#define STG_AS(b, s, kt)                                                                  \
    async16(Abase + (size_t)((s) * 64) * Kdim + (kt) * 64,                                \
            ldstA + (b) * 32768 + (s) * 8192)
    // B half h (128 rows) of K-tile kt -> buf b: TWO async16
#define STG_B(b, h, kt) do {                                                              \
    async16(Bbase + (size_t)((h) * 128) * Kdim + (kt) * 64,                               \
            ldstB + (b) * 32768 + (h) * 16384);                                           \
    async16(Bbase + (size_t)((h) * 128 + 64) * Kdim + (kt) * 64,                          \
            ldstB + (b) * 32768 + (h) * 16384 + 8192); } while (0)

    // ---- prologue: buf0 full (kt0), then B-buf1 (kt1); A-buf1 staged in-loop P1/P2 ----
    STG_B(0, 0, 0); STG_B(0, 1, 0);
    STG_AS(0, 0, 0); STG_AS(0, 1, 0); STG_AS(0, 2, 0); STG_AS(0, 3, 0);
    STG_B(1, 0, 1); STG_B(1, 1, 1);
    asm volatile("s_waitcnt vmcnt(4)" ::: "memory");   // buf0 landed; B-buf1 in flight
    __builtin_amdgcn_sched_barrier(0);
    __builtin_amdgcn_s_barrier();
    __builtin_amdgcn_sched_barrier(0);

    // ---- ds_read lane bases (XOR-swizzled; bank-conflict-free, verified r1/r2/r4) ----
    const int koff0 = ((hi ^ (lo & 3)) << 4) + (((lo >> 2) & 1) << 6);
    const char* pA0 = smem + wr * 16384 + lo * 128 + koff0;
    const char* pA1 = smem + wr * 16384 + lo * 128 + (koff0 ^ 64);
    const char* pB0 = smem + 65536 + wc * 8192 + lo * 128 + koff0;
    const char* pB1 = smem + 65536 + wc * 8192 + lo * 128 + (koff0 ^ 64);

    f32x4 acc[8][4] = {};
    half8 bfr[4][2];

#define BARSEQ                                                                            \
    __builtin_amdgcn_sched_barrier(0);                                                    \
    __builtin_amdgcn_s_barrier();                                                         \
    __builtin_amdgcn_sched_barrier(0);

#define LDA4(b, q, A00, A01, A10, A11)                                                    \
    half8 A00 = *(const half8*)(pA0 + (b) * 32768 + (q) * 4096);                          \
    half8 A01 = *(const half8*)(pA1 + (b) * 32768 + (q) * 4096);                          \
    half8 A10 = *(const half8*)(pA0 + (b) * 32768 + (q) * 4096 + 2048);                   \
    half8 A11 = *(const half8*)(pA1 + (b) * 32768 + (q) * 4096 + 2048);

#define LDB8(b)                                                                           \
    bfr[0][0] = *(const half8*)(pB0 + (b) * 32768 + 0 * 2048);                            \
    bfr[0][1] = *(const half8*)(pB1 + (b) * 32768 + 0 * 2048);                            \
    bfr[1][0] = *(const half8*)(pB0 + (b) * 32768 + 1 * 2048);                            \
    bfr[1][1] = *(const half8*)(pB1 + (b) * 32768 + 1 * 2048);                            \
    bfr[2][0] = *(const half8*)(pB0 + (b) * 32768 + 2 * 2048);                            \
    bfr[2][1] = *(const half8*)(pB1 + (b) * 32768 + 2 * 2048);                            \
    bfr[3][0] = *(const half8*)(pB0 + (b) * 32768 + 3 * 2048);                            \
    bfr[3][1] = *(const half8*)(pB1 + (b) * 32768 + 3 * 2048);

#define MFMAQ(q, A00, A01, A10, A11)                                                      \
    __builtin_amdgcn_s_setprio(1);                                                        \
    acc[2*(q)][0]   = MFMA16(A00, bfr[0][0], acc[2*(q)][0],   0, 0, 0);                   \
    acc[2*(q)][1]   = MFMA16(A00, bfr[1][0], acc[2*(q)][1],   0, 0, 0);                   \
    acc[2*(q)][2]   = MFMA16(A00, bfr[2][0], acc[2*(q)][2],   0, 0, 0);                   \
    acc[2*(q)][3]   = MFMA16(A00, bfr[3][0], acc[2*(q)][3],   0, 0, 0);                   \
    acc[2*(q)+1][0] = MFMA16(A10, bfr[0][0], acc[2*(q)+1][0], 0, 0, 0);                   \
    acc[2*(q)+1][1] = MFMA16(A10, bfr[1][0], acc[2*(q)+1][1], 0, 0, 0);                   \
    acc[2*(q)+1][2] = MFMA16(A10, bfr[2][0], acc[2*(q)+1][2], 0, 0, 0);                   \
    acc[2*(q)+1][3] = MFMA16(A10, bfr[3][0], acc[2*(q)+1][3], 0, 0, 0);                   \
    acc[2*(q)][0]   = MFMA16(A01, bfr[0][1], acc[2*(q)][0],   0, 0, 0);                   \
    acc[2*(q)][1]   = MFMA16(A01, bfr[1][1], acc[2*(q)][1],   0, 0, 0);                   \
    acc[2*(q)][2]   = MFMA16(A01, bfr[2][1], acc[2*(q)][2],   0, 0, 0);                   \
    acc[2*(q)][3]   = MFMA16(A01, bfr[3][1], acc[2*(q)][3],   0, 0, 0);                   \
    acc[2*(q)+1][0] = MFMA16(A11, bfr[0][1], acc[2*(q)+1][0], 0, 0, 0);                   \
    acc[2*(q)+1][1] = MFMA16(A11, bfr[1][1], acc[2*(q)+1][1], 0, 0, 0);                   \
    acc[2*(q)+1][2] = MFMA16(A11, bfr[2][1], acc[2*(q)+1][2], 0, 0, 0);                   \
    acc[2*(q)+1][3] = MFMA16(A11, bfr[3][1], acc[2*(q)+1][3], 0, 0, 0);                   \
    __builtin_amdgcn_s_setprio(0);

    for (int i = 0; i < NITER; ++i) {
        const int kA1  = 2 * i + 1;                // A-buf1 content (read P5-P8 this iter)
        const int ktn0 = (2 * i + 2) & (NKT - 1);  // next buf0 (last iter: wraps -> dead)
        const int ktn1 = (2 * i + 3) & (NKT - 1);  // next buf1-B (wraps -> dead)

        // ---- P1: B(buf0) + A(buf0,q0); stage A1 slices 0,2 ----
        {
            LDB8(0)
            LDA4(0, 0, a00, a01, a10, a11)
            STG_AS(1, 0, kA1); STG_AS(1, 2, kA1);
            BARSEQ
            MFMAQ(0, a00, a01, a10, a11)
        }
        // ---- P2: A(buf0,q1); stage A1 slices 1,3 ----
        {
            LDA4(0, 1, a00, a01, a10, a11)
            STG_AS(1, 1, kA1); STG_AS(1, 3, kA1);
            BARSEQ
            MFMAQ(1, a00, a01, a10, a11)
        }
        // ---- P3: A(buf0,q2); stage B0h0' ----
        {
            LDA4(0, 2, a00, a01, a10, a11)
            STG_B(0, 0, ktn0);
            BARSEQ
            MFMAQ(2, a00, a01, a10, a11)
        }
        // ---- P4: A(buf0,q3); stage B0h1'; GATE vmcnt(4) -> buf1 fully landed ----
        {
            LDA4(0, 3, a00, a01, a10, a11)
            STG_B(0, 1, ktn0);
            asm volatile("s_waitcnt vmcnt(4)" ::: "memory");
            BARSEQ
            MFMAQ(3, a00, a01, a10, a11)
        }
        // ---- P5: B(buf1) + A(buf1,q0); stage A0 slices 0,2' ----
        {
            LDB8(1)
            LDA4(1, 0, a00, a01, a10, a11)
            STG_AS(0, 0, ktn0); STG_AS(0, 2, ktn0);
            BARSEQ
            MFMAQ(0, a00, a01, a10, a11)
        }
        // ---- P6: A(buf1,q1); stage A0 slices 1,3' ----
        {
            LDA4(1, 1, a00, a01, a10, a11)
            STG_AS(0, 1, ktn0); STG_AS(0, 3, ktn0);
            BARSEQ
            MFMAQ(1, a00, a01, a10, a11)
        }
        // ---- P7: A(buf1,q2); stage B1h0' ----
        {
            LDA4(1, 2, a00, a01, a10, a11)
            STG_B(1, 0, ktn1);
            BARSEQ
            MFMAQ(2, a00, a01, a10, a11)
        }
        // ---- P8: A(buf1,q3); stage B1h1'; GATE vmcnt(4) -> buf0' fully landed ----
        {
            LDA4(1, 3, a00, a01, a10, a11)
            STG_B(1, 1, ktn1);
            asm volatile("s_waitcnt vmcnt(4)" ::: "memory");
            BARSEQ
            MFMAQ(3, a00, a01, a10, a11)
        }
    }

    // drain in-flight dead stages before workgroup teardown
    asm volatile("s_waitcnt vmcnt(0)" ::: "memory");

    // ---- epilogue: bias + fp32 store (acc[m] row = 128wr + 16m + 4hi + r) ----
    const int rbase = tm * 256 + wr * 128;
    const int cbase = tn * 256 + wc * 64;
    float bv0 = bias[cbase + 0 * 16 + lo];
    float bv1 = bias[cbase + 1 * 16 + lo];
    float bv2 = bias[cbase + 2 * 16 + lo];
    float bv3 = bias[cbase + 3 * 16 + lo];
#pragma unroll
    for (int m = 0; m < 8; ++m) {
        const int r0r = rbase + m * 16 + hi * 4;
#pragma unroll
        for (int r = 0; r < 4; ++r) {
            float* crow = C + (size_t)(r0r + r) * Ndim + cbase + lo;
            crow[0]  = acc[m][0][r] + bv0;
            crow[16] = acc[m][1][r] + bv1;
            crow[32] = acc[m][2][r] + bv2;
            crow[48] = acc[m][3][r] + bv3;
        }
    }
}

// ---------------------------------------------------------------------------
extern "C" void kernel_launch(void* const* d_in, const int* in_sizes, int n_in,
                              void* d_out, int out_size, void* d_ws, size_t ws_size,
                              hipStream_t stream) {
    const float* x = (const float*)d_in[0];
    const float* w = (const float*)d_in[1];
    const float* bias = (const float*)d_in[2];
    float* out = (float*)d_out;

    if (in_sizes[2] != Ndim || in_sizes[1] != Ndim * Kdim || in_sizes[0] != Mdim * Kdim)
        return;  // shape-specialized; fail loudly

    const size_t xq_bytes = (size_t)Mdim * Kdim * sizeof(half_t);
    const size_t wq_bytes = (size_t)Ndim * Kdim * sizeof(half_t);
    if (ws_size < xq_bytes + wq_bytes) return;

    half_t* xq = (half_t*)d_ws;
    half_t* wq = (half_t*)((char*)d_ws + xq_bytes);

    quant_kernel<<<dim3(Kdim / 128, Mdim / 128), 256, 0, stream>>>(x, xq, Kdim);
    quant_kernel<<<dim3(Kdim / 128, Ndim / 128), 256, 0, stream>>>(w, wq, Kdim);

    (void)hipFuncSetAttribute((const void*)gemm_kernel,
                              hipFuncAttributeMaxDynamicSharedMemorySize, LDS_BYTES);

    gemm_kernel<<<dim3(NTM * NTN), dim3(512), LDS_BYTES, stream>>>(xq, wq, bias, out);
}